// Round 6
// baseline (142.171 us; speedup 1.0000x reference)
//
#include <hip/hip_runtime.h>
#include <hip/hip_bf16.h>
#include <stdint.h>

#define G_ 24
#define B_ 256
#define I_ 512
#define E_ 512
#define K_ (G_ * I_)   // 12288
// splitK=4, BK=32: 96 k-steps per WG. Grid 768 = 2m x 4n x 24h x 4s = 3 WG/CU exact.

typedef __hip_bfloat16 bf16;
typedef __bf16 bf16x8 __attribute__((ext_vector_type(8)));
typedef float f32x4 __attribute__((ext_vector_type(4)));

// ---------- input f32 -> bf16 ----------
__global__ void cvt_in_kernel(const float* __restrict__ in, bf16* __restrict__ out, int n4) {
  int idx = blockIdx.x * blockDim.x + threadIdx.x;
  if (idx >= n4) return;
  float4 v = reinterpret_cast<const float4*>(in)[idx];
  union { bf16 h[4]; uint2 u; } pk;
  pk.h[0] = __float2bfloat16(v.x);
  pk.h[1] = __float2bfloat16(v.y);
  pk.h[2] = __float2bfloat16(v.z);
  pk.h[3] = __float2bfloat16(v.w);
  reinterpret_cast<uint2*>(out)[idx] = pk.u;
}

// ---------- W[g][i][e] f32 -> Wt[g][e][i] bf16 ----------
__global__ void transpose_w_kernel(const float* __restrict__ W, bf16* __restrict__ Wt) {
  __shared__ float tile[32][33];
  const int g = blockIdx.z;
  const int i0 = blockIdx.x * 32;
  const int e0 = blockIdx.y * 32;
  const float* src = W + (size_t)g * (I_ * E_) + (size_t)(i0 + threadIdx.y) * E_ + e0 + threadIdx.x;
  #pragma unroll
  for (int r = 0; r < 32; r += 8)
    tile[threadIdx.y + r][threadIdx.x] = src[(size_t)r * E_];
  __syncthreads();
  bf16* dst = Wt + (size_t)g * (I_ * E_) + (size_t)(e0 + threadIdx.y) * I_ + i0 + threadIdx.x;
  #pragma unroll
  for (int r = 0; r < 32; r += 8)
    dst[(size_t)r * I_] = __float2bfloat16(tile[threadIdx.x][threadIdx.y + r]);
}

// ---------- out[b][h][e] = bias[e] ----------
__global__ void init_out_kernel(const float* __restrict__ bias, float* __restrict__ out, int n4) {
  int idx = blockIdx.x * blockDim.x + threadIdx.x;
  if (idx >= n4) return;
  int e4 = idx & 127;  // (E/4)=128 float4 per (b,h) row
  reinterpret_cast<float4*>(out)[idx] = reinterpret_cast<const float4*>(bias)[e4];
}

// ================= GEMM: BM=128, BN=128, BK=32, 4 waves of 64x64, splitK=4 =================
// out[b,h,e] += sum_k A[b,k] * Wt[(k/512 - h)%24][e][k%512]
// LDS 32 KB dbuf -> 3 WG/CU; grid 768 = exactly one uniform round.
// XCD x = bid&7 <-> (m-half = x&1, split = x>>1): per-XCD 96 WGs (24h x 4n) share
// one 8 KB A-window per k-step; W set = 24 gsrc x [512e][32i] per step, 1.5 MB per
// g-block reused over 16 steps -> ~9.75 MB L2 traffic per XCD.
// All ds_read offsets and staging source offsets are loop-invariant (BK=32 ->
// kslot = lane>>4); staging bases advance by uniform increments.
// Swizzle (both sides): row's four 16B slots permuted by ((row>>1)&3);
// LDS dest stays linear for global_load_lds; source + ds_read use the XOR.
#define FENCE() asm volatile("" ::: "memory")
#define BAR()   __builtin_amdgcn_s_barrier()
#define VMW(N)  asm volatile("s_waitcnt vmcnt(" #N ")" ::: "memory")

__device__ __forceinline__ void gload16(const bf16* g, bf16* l) {
  __builtin_amdgcn_global_load_lds((const __attribute__((address_space(1))) void*)g,
                                   (__attribute__((address_space(3))) void*)l, 16, 0, 0);
}

__global__ __launch_bounds__(256, 3) void gemm_kernel(
    const bf16* __restrict__ A,   // [256][12288]
    const bf16* __restrict__ Wt,  // [24][512(e)][512(i)]
    float* __restrict__ out) {    // [256][24][512], pre-init'd with bias

  __shared__ __align__(16) bf16 ldsA[2][128 * 32];  // 16 KB
  __shared__ __align__(16) bf16 ldsB[2][128 * 32];  // 16 KB

  const int tid  = threadIdx.x;
  const int lane = tid & 63;
  const int wave = tid >> 6;     // 0..3
  const int wr   = wave >> 1;    // 0..1 -> 64 M-rows
  const int wc   = wave & 1;     // 0..1 -> 64 N-cols
  const int rsel = lane & 15;
  const int q    = lane >> 4;    // k-slot 0..3 (8 bf16 each)

  // XCD-local decode
  const int bid   = blockIdx.x;        // 0..767
  const int xcd   = bid & 7;
  const int m0    = (xcd & 1) * 128;
  const int s     = xcd >> 1;          // split 0..3
  const int inner = bid >> 3;          // 0..95
  const int n0    = (inner & 3) * 128;
  const int h     = inner >> 2;        // 0..23

  // ---- loop-invariant staging offsets (2 chunks per thread per tile) ----
  // chunk c: row = c>>2, linear slot = c&3, source slot = (c&3) ^ ((c>>3)&3)
  const int c0 = tid, c1 = tid + 256;
  const size_t aoff0 = (size_t)(c0 >> 2) * K_ + (((c0 & 3) ^ ((c0 >> 3) & 3)) << 3);
  const size_t aoff1 = (size_t)(c1 >> 2) * K_ + (((c1 & 3) ^ ((c1 >> 3) & 3)) << 3);
  const size_t boff0 = (size_t)(c0 >> 2) * I_ + (((c0 & 3) ^ ((c0 >> 3) & 3)) << 3);
  const size_t boff1 = (size_t)(c1 >> 2) * I_ + (((c1 & 3) ^ ((c1 >> 3) & 3)) << 3);

  // ---- loop-invariant ds_read byte offsets (within one 8 KB buffer) ----
  int aro[4], bro[4];
  #pragma unroll
  for (int mi = 0; mi < 4; ++mi) {
    int r = wr * 64 + mi * 16 + rsel;
    aro[mi] = r * 64 + ((q ^ ((r >> 1) & 3)) << 4);
  }
  #pragma unroll
  for (int ni = 0; ni < 4; ++ni) {
    int r = wc * 64 + ni * 16 + rsel;
    bro[ni] = r * 64 + ((q ^ ((r >> 1) & 3)) << 4);
  }

  f32x4 acc[4][4];
  #pragma unroll
  for (int i = 0; i < 4; ++i)
    #pragma unroll
    for (int j = 0; j < 4; ++j)
      acc[i][j] = (f32x4){0.f, 0.f, 0.f, 0.f};

  // stage k-step t (0..95) into buffer b
  auto stage = [&](int t, int b) {
    const int gloc  = t >> 4;          // g-block within split (0..5)
    const int gamma = t & 15;          // i-offset step within g
    int gsrc = s * 6 + gloc - h;
    if (gsrc < 0) gsrc += G_;
    if (gsrc >= G_) gsrc -= G_;
    const bf16* Ab = A + (size_t)m0 * K_ + ((size_t)s * 96 + t) * 32;
    const bf16* Bb = Wt + (size_t)gsrc * (I_ * E_) + (size_t)n0 * I_ + gamma * 32;
    gload16(Ab + aoff0, &ldsA[b][(size_t)c0 * 8]);
    gload16(Ab + aoff1, &ldsA[b][(size_t)c1 * 8]);
    gload16(Bb + boff0, &ldsB[b][(size_t)c0 * 8]);
    gload16(Bb + boff1, &ldsB[b][(size_t)c1 * 8]);
  };

#define STEP(LT, CB, NB) do {                                                    \
    if ((LT) + 1 < 96) { stage((LT) + 1, NB); VMW(4); } else { VMW(0); }         \
    FENCE(); BAR(); FENCE();                                                     \
    bf16x8 af[4], bfr[4];                                                        \
    _Pragma("unroll") for (int mi = 0; mi < 4; ++mi)                             \
      af[mi] = *(const bf16x8*)((const char*)(&ldsA[CB][0]) + aro[mi]);          \
    _Pragma("unroll") for (int ni = 0; ni < 4; ++ni)                             \
      bfr[ni] = *(const bf16x8*)((const char*)(&ldsB[CB][0]) + bro[ni]);         \
    _Pragma("unroll") for (int mi = 0; mi < 4; ++mi)                             \
      _Pragma("unroll") for (int ni = 0; ni < 4; ++ni)                           \
        acc[mi][ni] = __builtin_amdgcn_mfma_f32_16x16x32_bf16(                   \
            af[mi], bfr[ni], acc[mi][ni], 0, 0, 0);                              \
    asm volatile("s_waitcnt lgkmcnt(0)" ::: "memory");                           \
    BAR(); FENCE();                                                              \
  } while (0)

  stage(0, 0);
  for (int lt = 0; lt < 96; lt += 2) {
    STEP(lt, 0, 1);
    STEP(lt + 1, 1, 0);
  }
#undef STEP

  // ---- epilogue: atomic split-K combine. C/D: col=lane&15, row=(lane>>4)*4+reg
  #pragma unroll
  for (int mi = 0; mi < 4; ++mi) {
    #pragma unroll
    for (int ni = 0; ni < 4; ++ni) {
      int ecol  = n0 + wc * 64 + ni * 16 + rsel;
      int brow0 = m0 + wr * 64 + mi * 16 + q * 4;
      float* o = out + (size_t)brow0 * (G_ * E_) + (size_t)h * E_ + ecol;
      #pragma unroll
      for (int r = 0; r < 4; ++r)
        atomicAdd(o + (size_t)r * (G_ * E_), acc[mi][ni][r]);
    }
  }
}

extern "C" void kernel_launch(void* const* d_in, const int* in_sizes, int n_in,
                              void* d_out, int out_size, void* d_ws, size_t ws_size,
                              hipStream_t stream) {
  const float* in   = (const float*)d_in[0];
  const float* w    = (const float*)d_in[1];
  const float* bias = (const float*)d_in[2];
  float* out = (float*)d_out;

  bf16* A_bf = (bf16*)d_ws;                                   // 6.29 MB
  bf16* Wt   = (bf16*)((char*)d_ws + (size_t)B_ * K_ * 2);    // 12.58 MB

  const int n4in  = (B_ * K_) / 4;        // 786432
  const int n4out = (B_ * G_ * E_) / 4;   // 786432
  cvt_in_kernel<<<n4in / 256, 256, 0, stream>>>(in, A_bf, n4in);
  transpose_w_kernel<<<dim3(E_ / 32, I_ / 32, G_), dim3(32, 8), 0, stream>>>(w, Wt);
  init_out_kernel<<<n4out / 256, 256, 0, stream>>>(bias, out, n4out);
  gemm_kernel<<<768, 256, 0, stream>>>(A_bf, Wt, out);
}

// Round 7
// 131.112 us; speedup vs baseline: 1.0843x; 1.0843x over previous
//
#include <hip/hip_runtime.h>
#include <hip/hip_bf16.h>
#include <stdint.h>

#define G_ 24
#define B_ 256
#define I_ 512
#define E_ 512
#define K_ (G_ * I_)   // 12288
// splitK=4, BK=32: 96 k-steps per WG. Grid 768 = 2m x 4n x 24h x 4s = 3 WG/CU exact.

typedef __hip_bfloat16 bf16;
typedef __bf16 bf16x8 __attribute__((ext_vector_type(8)));
typedef float f32x4 __attribute__((ext_vector_type(4)));

// ---------- input f32 -> bf16 ----------
__global__ void cvt_in_kernel(const float* __restrict__ in, bf16* __restrict__ out, int n4) {
  int idx = blockIdx.x * blockDim.x + threadIdx.x;
  if (idx >= n4) return;
  float4 v = reinterpret_cast<const float4*>(in)[idx];
  union { bf16 h[4]; uint2 u; } pk;
  pk.h[0] = __float2bfloat16(v.x);
  pk.h[1] = __float2bfloat16(v.y);
  pk.h[2] = __float2bfloat16(v.z);
  pk.h[3] = __float2bfloat16(v.w);
  reinterpret_cast<uint2*>(out)[idx] = pk.u;
}

// ---------- W[g][i][e] f32 -> Wt[g][e][i] bf16 ----------
__global__ void transpose_w_kernel(const float* __restrict__ W, bf16* __restrict__ Wt) {
  __shared__ float tile[32][33];
  const int g = blockIdx.z;
  const int i0 = blockIdx.x * 32;
  const int e0 = blockIdx.y * 32;
  const float* src = W + (size_t)g * (I_ * E_) + (size_t)(i0 + threadIdx.y) * E_ + e0 + threadIdx.x;
  #pragma unroll
  for (int r = 0; r < 32; r += 8)
    tile[threadIdx.y + r][threadIdx.x] = src[(size_t)r * E_];
  __syncthreads();
  bf16* dst = Wt + (size_t)g * (I_ * E_) + (size_t)(e0 + threadIdx.y) * I_ + i0 + threadIdx.x;
  #pragma unroll
  for (int r = 0; r < 32; r += 8)
    dst[(size_t)r * I_] = __float2bfloat16(tile[threadIdx.x][threadIdx.y + r]);
}

// ---------- out[b][h][e] = bias[e] ----------
__global__ void init_out_kernel(const float* __restrict__ bias, float* __restrict__ out, int n4) {
  int idx = blockIdx.x * blockDim.x + threadIdx.x;
  if (idx >= n4) return;
  int e4 = idx & 127;  // (E/4)=128 float4 per (b,h) row
  reinterpret_cast<float4*>(out)[idx] = reinterpret_cast<const float4*>(bias)[e4];
}

// ================= GEMM: BM=128, BN=128, BK=32, 4 waves of 64x64, splitK=4 =================
// out[b,h,e] += sum_k A[b,k] * Wt[(k/512 - h)%24][e][k%512]
// LDS 32 KB dbuf -> 3 WG/CU; grid 768 = exactly one uniform round.
// XCD decode (xcd = bid&7, HW round-robin): bit0 -> m0, bits1-2 -> n0. Each XCD
// holds a FIXED (m0, n0) quarter with all 24h x 4s: W footprint/XCD =
// 24g x 128e x 512i x 2B = 3.1 MB (L2-resident, each tile shared by 4 (h,s) WGs
// per step); A window/step shared by 24 h-WGs. This reproduces R2's clean-fetch
// property (bid&7 pinned the n-slice there) with R6's low-VALU loop.
// All ds_read offsets and staging source offsets are loop-invariant (BK=32 ->
// kslot = lane>>4); staging bases advance by uniform increments.
// Swizzle (both sides): row's four 16B slots permuted by ((row>>1)&3);
// LDS dest stays linear for global_load_lds; source + ds_read use the XOR.
#define FENCE() asm volatile("" ::: "memory")
#define BAR()   __builtin_amdgcn_s_barrier()
#define VMW(N)  asm volatile("s_waitcnt vmcnt(" #N ")" ::: "memory")

__device__ __forceinline__ void gload16(const bf16* g, bf16* l) {
  __builtin_amdgcn_global_load_lds((const __attribute__((address_space(1))) void*)g,
                                   (__attribute__((address_space(3))) void*)l, 16, 0, 0);
}

__global__ __launch_bounds__(256, 3) void gemm_kernel(
    const bf16* __restrict__ A,   // [256][12288]
    const bf16* __restrict__ Wt,  // [24][512(e)][512(i)]
    float* __restrict__ out) {    // [256][24][512], pre-init'd with bias

  __shared__ __align__(16) bf16 ldsA[2][128 * 32];  // 16 KB
  __shared__ __align__(16) bf16 ldsB[2][128 * 32];  // 16 KB

  const int tid  = threadIdx.x;
  const int lane = tid & 63;
  const int wave = tid >> 6;     // 0..3
  const int wr   = wave >> 1;    // 0..1 -> 64 M-rows
  const int wc   = wave & 1;     // 0..1 -> 64 N-cols
  const int rsel = lane & 15;
  const int q    = lane >> 4;    // k-slot 0..3 (8 bf16 each)

  // XCD-pinned decode: xcd = bid&7 fixes (m0, n0); inner spans (s, h).
  const int bid   = blockIdx.x;        // 0..767
  const int m0    = (bid & 1) * 128;
  const int n0    = ((bid >> 1) & 3) * 128;
  const int inner = bid >> 3;          // 0..95
  const int s     = inner & 3;         // split 0..3
  const int h     = inner >> 2;        // 0..23

  // ---- loop-invariant staging offsets (2 chunks per thread per tile) ----
  // chunk c: row = c>>2, linear slot = c&3, source slot = (c&3) ^ ((c>>3)&3)
  const int c0 = tid, c1 = tid + 256;
  const size_t aoff0 = (size_t)(c0 >> 2) * K_ + (((c0 & 3) ^ ((c0 >> 3) & 3)) << 3);
  const size_t aoff1 = (size_t)(c1 >> 2) * K_ + (((c1 & 3) ^ ((c1 >> 3) & 3)) << 3);
  const size_t boff0 = (size_t)(c0 >> 2) * I_ + (((c0 & 3) ^ ((c0 >> 3) & 3)) << 3);
  const size_t boff1 = (size_t)(c1 >> 2) * I_ + (((c1 & 3) ^ ((c1 >> 3) & 3)) << 3);

  // ---- loop-invariant ds_read byte offsets (within one 8 KB buffer) ----
  int aro[4], bro[4];
  #pragma unroll
  for (int mi = 0; mi < 4; ++mi) {
    int r = wr * 64 + mi * 16 + rsel;
    aro[mi] = r * 64 + ((q ^ ((r >> 1) & 3)) << 4);
  }
  #pragma unroll
  for (int ni = 0; ni < 4; ++ni) {
    int r = wc * 64 + ni * 16 + rsel;
    bro[ni] = r * 64 + ((q ^ ((r >> 1) & 3)) << 4);
  }

  f32x4 acc[4][4];
  #pragma unroll
  for (int i = 0; i < 4; ++i)
    #pragma unroll
    for (int j = 0; j < 4; ++j)
      acc[i][j] = (f32x4){0.f, 0.f, 0.f, 0.f};

  // stage k-step t (0..95) into buffer b
  auto stage = [&](int t, int b) {
    const int gloc  = t >> 4;          // g-block within split (0..5)
    const int gamma = t & 15;          // i-offset step within g
    int gsrc = s * 6 + gloc - h;
    if (gsrc < 0) gsrc += G_;
    if (gsrc >= G_) gsrc -= G_;
    const bf16* Ab = A + (size_t)m0 * K_ + ((size_t)s * 96 + t) * 32;
    const bf16* Bb = Wt + (size_t)gsrc * (I_ * E_) + (size_t)n0 * I_ + gamma * 32;
    gload16(Ab + aoff0, &ldsA[b][(size_t)c0 * 8]);
    gload16(Ab + aoff1, &ldsA[b][(size_t)c1 * 8]);
    gload16(Bb + boff0, &ldsB[b][(size_t)c0 * 8]);
    gload16(Bb + boff1, &ldsB[b][(size_t)c1 * 8]);
  };

#define STEP(LT, CB, NB) do {                                                    \
    if ((LT) + 1 < 96) { stage((LT) + 1, NB); VMW(4); } else { VMW(0); }         \
    FENCE(); BAR(); FENCE();                                                     \
    bf16x8 af[4], bfr[4];                                                        \
    _Pragma("unroll") for (int mi = 0; mi < 4; ++mi)                             \
      af[mi] = *(const bf16x8*)((const char*)(&ldsA[CB][0]) + aro[mi]);          \
    _Pragma("unroll") for (int ni = 0; ni < 4; ++ni)                             \
      bfr[ni] = *(const bf16x8*)((const char*)(&ldsB[CB][0]) + bro[ni]);         \
    _Pragma("unroll") for (int mi = 0; mi < 4; ++mi)                             \
      _Pragma("unroll") for (int ni = 0; ni < 4; ++ni)                           \
        acc[mi][ni] = __builtin_amdgcn_mfma_f32_16x16x32_bf16(                   \
            af[mi], bfr[ni], acc[mi][ni], 0, 0, 0);                              \
    asm volatile("s_waitcnt lgkmcnt(0)" ::: "memory");                           \
    BAR(); FENCE();                                                              \
  } while (0)

  stage(0, 0);
  for (int lt = 0; lt < 96; lt += 2) {
    STEP(lt, 0, 1);
    STEP(lt + 1, 1, 0);
  }
#undef STEP

  // ---- epilogue: atomic split-K combine. C/D: col=lane&15, row=(lane>>4)*4+reg
  #pragma unroll
  for (int mi = 0; mi < 4; ++mi) {
    #pragma unroll
    for (int ni = 0; ni < 4; ++ni) {
      int ecol  = n0 + wc * 64 + ni * 16 + rsel;
      int brow0 = m0 + wr * 64 + mi * 16 + q * 4;
      float* o = out + (size_t)brow0 * (G_ * E_) + (size_t)h * E_ + ecol;
      #pragma unroll
      for (int r = 0; r < 4; ++r)
        atomicAdd(o + (size_t)r * (G_ * E_), acc[mi][ni][r]);
    }
  }
}

extern "C" void kernel_launch(void* const* d_in, const int* in_sizes, int n_in,
                              void* d_out, int out_size, void* d_ws, size_t ws_size,
                              hipStream_t stream) {
  const float* in   = (const float*)d_in[0];
  const float* w    = (const float*)d_in[1];
  const float* bias = (const float*)d_in[2];
  float* out = (float*)d_out;

  bf16* A_bf = (bf16*)d_ws;                                   // 6.29 MB
  bf16* Wt   = (bf16*)((char*)d_ws + (size_t)B_ * K_ * 2);    // 12.58 MB

  const int n4in  = (B_ * K_) / 4;        // 786432
  const int n4out = (B_ * G_ * E_) / 4;   // 786432
  cvt_in_kernel<<<n4in / 256, 256, 0, stream>>>(in, A_bf, n4in);
  transpose_w_kernel<<<dim3(E_ / 32, I_ / 32, G_), dim3(32, 8), 0, stream>>>(w, Wt);
  init_out_kernel<<<n4out / 256, 256, 0, stream>>>(bias, out, n4out);
  gemm_kernel<<<768, 256, 0, stream>>>(A_bf, Wt, out);
}